// Round 18
// baseline (1923.196 us; speedup 1.0000x reference)
//
#include <hip/hip_runtime.h>
#include <hip/hip_bf16.h>
#include <math.h>

#define BT_   2048
#define D_    768
#define T_    1024
#define H_    12
#define HD_   64
#define L_    12
#define V_    50257
#define VPAD_ 50304    // 393*128
#define NCHUNK_ 7168   // 56*128

typedef __hip_bfloat16 bf16;
typedef short bf16x8 __attribute__((ext_vector_type(8)));  // 8 bf16 = 4 VGPRs
typedef short s16x4 __attribute__((ext_vector_type(4)));
typedef float f32x4 __attribute__((ext_vector_type(4)));

// ---------------- embedding: wave-per-row, float4 (G13) ----------------
__global__ __launch_bounds__(256) void embed_kernel(const int* __restrict__ idx,
                                                    const float* __restrict__ wte,
                                                    const float* __restrict__ wpe,
                                                    float* __restrict__ x) {
    const int bt   = blockIdx.x * 4 + (threadIdx.x >> 6);
    const int lane = threadIdx.x & 63;
    const int t    = bt & (T_ - 1);
    const int tok  = idx[bt];
    const float* wrow = wte + (size_t)tok * D_;
    const float* prow = wpe + (size_t)t * D_;
    float* xrow = x + (size_t)bt * D_;
    #pragma unroll
    for (int i = 0; i < 3; i++) {
        const int d0 = (i * 64 + lane) * 4;
        f32x4 a = *(const f32x4*)&wrow[d0];
        f32x4 p = *(const f32x4*)&prow[d0];
        #pragma unroll
        for (int e = 0; e < 4; e++) a[e] += p[e];
        *(f32x4*)&xrow[d0] = a;
    }
}

// ---------------- layernorm: wave-per-row, float4 loads, packed stores ----------------
__global__ __launch_bounds__(256) void lnorm_kernel(const float* __restrict__ in,
                                                    const float* __restrict__ g,
                                                    const float* __restrict__ b,
                                                    bf16* __restrict__ out) {
    const int row  = blockIdx.x * 4 + (threadIdx.x >> 6);
    const int lane = threadIdx.x & 63;
    const float* xr = in + (size_t)row * D_;
    f32x4 v[3];
    float s = 0.f, s2 = 0.f;
    #pragma unroll
    for (int i = 0; i < 3; i++) {
        v[i] = *(const f32x4*)&xr[(i * 64 + lane) * 4];
        #pragma unroll
        for (int e = 0; e < 4; e++) { s += v[i][e]; s2 += v[i][e] * v[i][e]; }
    }
    #pragma unroll
    for (int o = 32; o >= 1; o >>= 1) {
        s  += __shfl_xor(s,  o);
        s2 += __shfl_xor(s2, o);
    }
    const float mu   = s / D_;
    const float var  = s2 / D_ - mu * mu;
    const float rstd = rsqrtf(var + 1e-5f);
    bf16* orow = out + (size_t)row * D_;
    #pragma unroll
    for (int i = 0; i < 3; i++) {
        const int d0 = (i * 64 + lane) * 4;
        f32x4 gv = *(const f32x4*)&g[d0];
        f32x4 bv = *(const f32x4*)&b[d0];
        s16x4 u;
        #pragma unroll
        for (int e = 0; e < 4; e++) {
            bf16 h = __float2bfloat16((v[i][e] - mu) * rstd * gv[e] + bv[e]);
            u[e] = *(short*)&h;
        }
        *(s16x4*)&orow[d0] = u;
    }
}

// ---------------- transpose-convert: W fp32 [K,N] -> Wt bf16 [N,K]; z = layer ----------------
__global__ __launch_bounds__(256) void convT_kernel(const float* __restrict__ W,
                                                    bf16* __restrict__ Wt,
                                                    int K, int ldW, int n_src0, int Nreal,
                                                    size_t sW, size_t sT) {
    W  += (size_t)blockIdx.z * sW;
    Wt += (size_t)blockIdx.z * sT;
    __shared__ float t[32][33];
    int tx = threadIdx.x & 31, ty = threadIdx.x >> 5;  // ty 0..7
    int k0 = blockIdx.y * 32, n0 = blockIdx.x * 32;
    #pragma unroll
    for (int i = 0; i < 4; i++) {
        int k = k0 + ty + i * 8;
        int n = n_src0 + n0 + tx;
        t[ty + i * 8][tx] = (n < Nreal) ? W[(size_t)k * ldW + n] : 0.f;
    }
    __syncthreads();
    #pragma unroll
    for (int i = 0; i < 4; i++)
        Wt[(size_t)(n0 + ty + i * 8) * K + k0 + tx] = __float2bfloat16(t[tx][ty + i * 8]);
}

__device__ inline float gelu_f(float v) {
    const float c = 0.7978845608028654f;
    float u = c * (v + 0.044715f * v * v * v);
    return 0.5f * v * (1.f + tanhf(u));
}

__device__ inline void gload16(const void* g, void* l) {
    __builtin_amdgcn_global_load_lds((const __attribute__((address_space(1))) void*)g,
                                     (__attribute__((address_space(3))) void*)l, 16, 0, 0);
}

// ============ PIPE=2 BK=64 body — ALL per-layer GEMMs ============
// r6/r17-proven discipline: vmcnt(G) top; COMPUTE; barrier; STAGE into just-read buf;
// last step peeled with vmcnt(0). 64x64 -> 32.8KB (4 blk/CU); 128x64 -> 49.2KB (3 blk/CU).
template <int BM, int BN, int WM, int WN, int EPI, typename OT>
__device__ __attribute__((always_inline)) void gemm_body64_p2(
        const bf16* __restrict__ A, const bf16* __restrict__ Bt,
        const float* __restrict__ bias, const float* res, OT* C,
        int K, int ldC, int n_off, int Ncap, int nx) {
    constexpr int NW = WM * WN;
    constexpr int MI = BM / WM / 16;
    constexpr int NJ = BN / WN / 16;
    constexpr int SA = (BM / 16) / NW;
    constexpr int SB = (BN / 16) / NW;
    constexpr int G  = 2 * (SA + SB);
    static_assert(SA >= 1 && SB >= 1, "stage mapping needs >=1 seg per wave");
    __shared__ __align__(16) short smem[2 * (BM + BN) * 64];
    short* Asm = smem;
    short* Bsm = smem + 2 * BM * 64;
    const int tid  = threadIdx.x;
    const int lane = tid & 63;
    const int wid  = tid >> 6;
    const int wm = wid / WN, wn = wid % WN;

    const int nwg = gridDim.x;
    const int bid = blockIdx.x;
    const int q8  = nwg >> 3, r8 = nwg & 7;
    const int xcd = bid & 7, off = bid >> 3;
    const int swz = (xcd < r8 ? xcd * (q8 + 1) : r8 * (q8 + 1) + (xcd - r8) * q8) + off;
    const int m0 = (swz % nx) * BM;
    const int n0 = (swz / nx) * BN;

    const int rS8 = lane >> 3;
    const int cS  = ((lane & 7) ^ rS8) * 8;
    const int fr = lane & 15;
    const int fq = lane >> 4;

    auto STAGE = [&](int buf, int k0) {
        #pragma unroll
        for (int s = 0; s < SA; s++) {
            const int seg = wid * SA + s;
            #pragma unroll
            for (int g = 0; g < 2; g++)
                gload16(A + (size_t)(m0 + seg * 16 + g * 8 + rS8) * K + k0 + cS,
                        &Asm[buf * BM * 64 + seg * 1024 + g * 512]);
        }
        #pragma unroll
        for (int s = 0; s < SB; s++) {
            const int seg = wid * SB + s;
            #pragma unroll
            for (int g = 0; g < 2; g++)
                gload16(Bt + (size_t)(n0 + seg * 16 + g * 8 + rS8) * K + k0 + cS,
                        &Bsm[buf * BN * 64 + seg * 1024 + g * 512]);
        }
    };

    f32x4 acc[MI][NJ] = {};

    auto COMPUTE = [&](int buf) {
        bf16x8 af[2][MI], bfr[2][NJ];
        #pragma unroll
        for (int kh = 0; kh < 2; kh++) {
            #pragma unroll
            for (int i = 0; i < MI; i++) {
                const int row = wm * (BM / WM) + i * 16 + fr;
                af[kh][i] = *(const bf16x8*)&Asm[buf * BM * 64 + row * 64 + (((kh * 4 + fq) ^ (fr & 7)) << 3)];
            }
            #pragma unroll
            for (int j = 0; j < NJ; j++) {
                const int row = wn * (BN / WN) + j * 16 + fr;
                bfr[kh][j] = *(const bf16x8*)&Bsm[buf * BN * 64 + row * 64 + (((kh * 4 + fq) ^ (fr & 7)) << 3)];
            }
        }
        __builtin_amdgcn_s_setprio(1);
        #pragma unroll
        for (int i = 0; i < MI; i++)
            #pragma unroll
            for (int j = 0; j < NJ; j++) {
                acc[i][j] = __builtin_amdgcn_mfma_f32_16x16x32_bf16(af[0][i], bfr[0][j], acc[i][j], 0, 0, 0);
                acc[i][j] = __builtin_amdgcn_mfma_f32_16x16x32_bf16(af[1][i], bfr[1][j], acc[i][j], 0, 0, 0);
            }
        __builtin_amdgcn_s_setprio(0);
    };

    const int nk = K / 64;
    STAGE(0, 0);
    STAGE(1, 64);
    int cur = 0;
    for (int ks = 0; ks < nk - 1; ks++) {
        asm volatile("s_waitcnt vmcnt(%0)" :: "n"(G) : "memory");   // stage ks landed
        __builtin_amdgcn_s_barrier();
        __builtin_amdgcn_sched_barrier(0);
        COMPUTE(cur);
        __builtin_amdgcn_sched_barrier(0);
        __builtin_amdgcn_s_barrier();           // all waves done reading buf[cur]
        __builtin_amdgcn_sched_barrier(0);
        if (ks + 2 < nk) STAGE(cur, (ks + 2) * 64);
        cur ^= 1;
    }
    asm volatile("s_waitcnt vmcnt(0)" ::: "memory");
    __builtin_amdgcn_s_barrier();
    __builtin_amdgcn_sched_barrier(0);
    COMPUTE(cur);

    #pragma unroll
    for (int j = 0; j < NJ; j++) {
        const int col = n_off + n0 + wn * (BN / WN) + j * 16 + fr;
        if (col >= Ncap) continue;
        const float bb = (EPI == 3) ? 0.f : bias[col];
        #pragma unroll
        for (int i = 0; i < MI; i++) {
            #pragma unroll
            for (int r = 0; r < 4; r++) {
                const int row = m0 + wm * (BM / WM) + i * 16 + fq * 4 + r;
                float v = acc[i][j][r] + bb;
                if (EPI == 1) v += res[(size_t)row * ldC + col];
                if (EPI == 2) v = gelu_f(v);
                if constexpr (sizeof(OT) == 2)
                    C[(size_t)row * ldC + col] = __float2bfloat16(v);
                else
                    C[(size_t)row * ldC + col] = v;
            }
        }
    }
}

// ============ BK=32 body — LM head only (pinned ~300us memory floor) ============
template <int BM, int BN, int WM, int WN, int EPI, int NGRP, typename OT>
__device__ __attribute__((always_inline)) void gemm_body(
        const bf16* __restrict__ A, const bf16* __restrict__ Bt,
        const float* __restrict__ bias, const float* res, OT* C,
        int K, int ldC, int n_off, int Ncap, int nx) {
    constexpr int NW = WM * WN;
    constexpr int MI = BM / WM / 16;
    constexpr int NJ = BN / WN / 16;
    constexpr int GA = (BM / 16) / NW;
    constexpr int GB = (BN / 16) / NW;
    constexpr int G  = GA + GB;
    static_assert(GA >= 1 && GB >= 1, "stage mapping needs >=1 seg per wave");
    __shared__ __align__(16) short smem[3 * (BM + BN) * 32];
    short* Asm = smem;
    short* Bsm = smem + 3 * BM * 32;
    const int tid  = threadIdx.x;
    const int lane = tid & 63;
    const int wid  = tid >> 6;
    const int wm = wid / WN, wn = wid % WN;

    const int nwg = gridDim.x;
    const int bid = blockIdx.x;
    const int q8  = nwg >> 3, r8 = nwg & 7;
    const int xcd = bid & 7, off = bid >> 3;
    const int swz = (xcd < r8 ? xcd * (q8 + 1) : r8 * (q8 + 1) + (xcd - r8) * q8) + off;
    int m0, n0;
    if constexpr (NGRP > 0) {
        const int Gsz = nx * NGRP;
        const int g = swz / Gsz, r = swz % Gsz;
        m0 = (r % nx) * BM;
        n0 = (g * NGRP + r / nx) * BN;
    } else {
        m0 = (swz % nx) * BM;
        n0 = (swz / nx) * BN;
    }

    const int rS = lane >> 2;
    const int cS = ((lane & 3) ^ ((lane >> 3) & 3)) * 8;
    const int fr = lane & 15;
    const int fq = lane >> 4;
    const int rc = (fq ^ ((fr >> 1) & 3)) * 8;

    auto STAGE = [&](int buf, int k0) {
        #pragma unroll
        for (int s = 0; s < GA; s++) {
            const int seg = wid * GA + s;
            gload16(A + (size_t)(m0 + seg * 16 + rS) * K + k0 + cS, &Asm[buf * BM * 32 + seg * 512]);
        }
        #pragma unroll
        for (int s = 0; s < GB; s++) {
            const int seg = wid * GB + s;
            gload16(Bt + (size_t)(n0 + seg * 16 + rS) * K + k0 + cS, &Bsm[buf * BN * 32 + seg * 512]);
        }
    };

    f32x4 acc[MI][NJ] = {};

    auto COMPUTE = [&](int buf) {
        bf16x8 af[MI], bfr[NJ];
        #pragma unroll
        for (int i = 0; i < MI; i++)
            af[i] = *(const bf16x8*)&Asm[buf * BM * 32 + (wm * (BM / WM) + i * 16 + fr) * 32 + rc];
        #pragma unroll
        for (int j = 0; j < NJ; j++)
            bfr[j] = *(const bf16x8*)&Bsm[buf * BN * 32 + (wn * (BN / WN) + j * 16 + fr) * 32 + rc];
        __builtin_amdgcn_s_setprio(1);
        #pragma unroll
        for (int i = 0; i < MI; i++)
            #pragma unroll
            for (int j = 0; j < NJ; j++)
                acc[i][j] = __builtin_amdgcn_mfma_f32_16x16x32_bf16(af[i], bfr[j], acc[i][j], 0, 0, 0);
        __builtin_amdgcn_s_setprio(0);
    };

    const int nk = K / 32;
    STAGE(0, 0);
    STAGE(1, 32);
    int cur = 0;
    for (int ks = 0; ks < nk - 1; ks++) {
        asm volatile("s_waitcnt vmcnt(%0)" :: "n"(G) : "memory");
        __builtin_amdgcn_s_barrier();
        __builtin_amdgcn_sched_barrier(0);
        if (ks + 2 < nk) {
            int nxt = cur + 2; if (nxt >= 3) nxt -= 3;
            STAGE(nxt, (ks + 2) * 32);
        }
        COMPUTE(cur);
        cur = (cur + 1 == 3) ? 0 : cur + 1;
    }
    asm volatile("s_waitcnt vmcnt(0)" ::: "memory");
    __builtin_amdgcn_s_barrier();
    __builtin_amdgcn_sched_barrier(0);
    COMPUTE(cur);

    #pragma unroll
    for (int j = 0; j < NJ; j++) {
        const int col = n_off + n0 + wn * (BN / WN) + j * 16 + fr;
        if (col >= Ncap) continue;
        const float bb = (EPI == 3) ? 0.f : bias[col];
        #pragma unroll
        for (int i = 0; i < MI; i++) {
            #pragma unroll
            for (int r = 0; r < 4; r++) {
                const int row = m0 + wm * (BM / WM) + i * 16 + fq * 4 + r;
                float v = acc[i][j][r] + bb;
                if (EPI == 1) v += res[(size_t)row * ldC + col];
                if (EPI == 2) v = gelu_f(v);
                if constexpr (sizeof(OT) == 2)
                    C[(size_t)row * ldC + col] = __float2bfloat16(v);
                else
                    C[(size_t)row * ldC + col] = v;
            }
        }
    }
}

// Named instantiations — all per-layer GEMMs on the PIPE=2 BK=64 body.
__global__ __launch_bounds__(256) void gemm_qkv(const bf16* A, const bf16* Bt, const float* bias,
                                                const float* res, bf16* C, int K, int ldC,
                                                int n_off, int Ncap, int nx) {
    gemm_body64_p2<128, 64, 2, 2, 0, bf16>(A, Bt, bias, res, C, K, ldC, n_off, Ncap, nx);
}
__global__ __launch_bounds__(256) void gemm_aproj(const bf16* A, const bf16* Bt, const float* bias,
                                                  const float* res, float* C, int K, int ldC,
                                                  int n_off, int Ncap, int nx) {
    gemm_body64_p2<64, 64, 2, 2, 1, float>(A, Bt, bias, res, C, K, ldC, n_off, Ncap, nx);
}
__global__ __launch_bounds__(256) void gemm_fc(const bf16* A, const bf16* Bt, const float* bias,
                                               const float* res, bf16* C, int K, int ldC,
                                               int n_off, int Ncap, int nx) {
    gemm_body64_p2<128, 64, 2, 2, 2, bf16>(A, Bt, bias, res, C, K, ldC, n_off, Ncap, nx);
}
__global__ __launch_bounds__(256) void gemm_mproj(const bf16* A, const bf16* Bt, const float* bias,
                                                  const float* res, float* C, int K, int ldC,
                                                  int n_off, int Ncap, int nx) {
    gemm_body64_p2<64, 64, 2, 2, 1, float>(A, Bt, bias, res, C, K, ldC, n_off, Ncap, nx);
}
__global__ __launch_bounds__(512) void gemm_lmhead(const bf16* A, const bf16* Bt, const float* bias,
                                                   const float* res, float* C, int K, int ldC,
                                                   int n_off, int Ncap, int nx) {
    gemm_body<128, 128, 4, 2, 3, 4, float>(A, Bt, bias, res, C, K, ldC, n_off, Ncap, nx);
}

// ---------------- MFMA flash attention (+ T5 setprio, r15-proven) ----------
__device__ inline unsigned pk_bf16(float a, float b) {
    __hip_bfloat16 ha = __float2bfloat16(a), hb = __float2bfloat16(b);
    unsigned short ua = *(unsigned short*)&ha, ub = *(unsigned short*)&hb;
    return (unsigned)ua | ((unsigned)ub << 16);
}

__global__ __launch_bounds__(256) void fattn_kernel(const bf16* __restrict__ qkv,
                                                    bf16* __restrict__ att) {
    const int qi  = 15 - blockIdx.x;
    const int bh  = blockIdx.y;
    const int h   = bh % H_;
    const int b   = bh / H_;
    const int q0  = qi * 64;
    const int tid = threadIdx.x;
    const int lane = tid & 63;
    const int w   = tid >> 6;
    const int fr  = lane & 15;
    const int fq  = lane >> 4;

    __shared__ __align__(16) short K_lds[64 * 64];
    __shared__ __align__(16) short Vt_lds[64 * 64];
    __shared__ __align__(16) short P_lds[4][16 * 80];

    const size_t base = (size_t)b * T_ * 2304;
    const int qrow = q0 + w * 16 + fr;

    bf16x8 qf[2];
    qf[0] = *(const bf16x8*)(qkv + base + (size_t)qrow * 2304 + h * 64 + fq * 8);
    qf[1] = *(const bf16x8*)(qkv + base + (size_t)qrow * 2304 + h * 64 + 32 + fq * 8);

    const int vj  = tid >> 2;
    const int vd0 = (tid & 3) * 16;

    f32x4 acc[4] = {};
    float m = -1e30f, l = 0.f;

    const int nt = qi + 1;
    for (int kt = 0; kt < nt; kt++) {
        const int j0 = kt * 64;

        #pragma unroll
        for (int p = 0; p < 2; p++) {
            const int jl  = p * 32 + w * 8 + (lane >> 3);
            const int chg = (lane & 7) ^ (jl & 7);
            gload16(qkv + base + (size_t)(j0 + jl) * 2304 + D_ + h * 64 + chg * 8,
                    &K_lds[(p * 32 + w * 8) * 64]);
        }
        {
            const bf16* vsrc = qkv + base + (size_t)(j0 + vj) * 2304 + 2 * D_ + h * 64 + vd0;
            bf16x8 v0 = *(const bf16x8*)vsrc;
            bf16x8 v1 = *(const bf16x8*)(vsrc + 8);
            #pragma unroll
            for (int e = 0; e < 8; e++) {
                Vt_lds[((vd0 + e) * 64 + vj) ^ (e << 3)]     = v0[e];
                Vt_lds[((vd0 + 8 + e) * 64 + vj) ^ (e << 3)] = v1[e];
            }
        }
        __syncthreads();

        f32x4 s[4];
        __builtin_amdgcn_s_setprio(1);
        #pragma unroll
        for (int jb = 0; jb < 4; jb++) {
            const int j = jb * 16 + fr;
            bf16x8 k0 = *(const bf16x8*)&K_lds[j * 64 + (((0 + fq) ^ (fr & 7)) << 3)];
            bf16x8 k1 = *(const bf16x8*)&K_lds[j * 64 + (((4 + fq) ^ (fr & 7)) << 3)];
            f32x4 z = {};
            z = __builtin_amdgcn_mfma_f32_16x16x32_bf16(k0, qf[0], z, 0, 0, 0);
            s[jb] = __builtin_amdgcn_mfma_f32_16x16x32_bf16(k1, qf[1], z, 0, 0, 0);
        }
        __builtin_amdgcn_s_setprio(0);

        const bool need_mask = (j0 + 63 > q0 + w * 16);
        float mx = -1e30f;
        #pragma unroll
        for (int jb = 0; jb < 4; jb++) {
            #pragma unroll
            for (int r = 0; r < 4; r++) {
                float v = s[jb][r] * 0.125f;
                if (need_mask && (j0 + jb * 16 + fq * 4 + r > qrow)) v = -1e30f;
                s[jb][r] = v;
                mx = fmaxf(mx, v);
            }
        }
        mx = fmaxf(mx, __shfl_xor(mx, 16));
        mx = fmaxf(mx, __shfl_xor(mx, 32));

        const float mnew  = fmaxf(m, mx);
        const float alpha = __expf(m - mnew);

        float ts = 0.f;
        #pragma unroll
        for (int jb = 0; jb < 4; jb++) {
            #pragma unroll
            for (int r = 0; r < 4; r++) {
                s[jb][r] = __expf(s[jb][r] - mnew);
                ts += s[jb][r];
            }
            *(unsigned*)&P_lds[w][fr * 80 + jb * 16 + fq * 4]     = pk_bf16(s[jb][0], s[jb][1]);
            *(unsigned*)&P_lds[w][fr * 80 + jb * 16 + fq * 4 + 2] = pk_bf16(s[jb][2], s[jb][3]);
        }
        ts += __shfl_xor(ts, 16);
        ts += __shfl_xor(ts, 32);
        l = l * alpha + ts;
        #pragma unroll
        for (int db = 0; db < 4; db++)
            #pragma unroll
            for (int r = 0; r < 4; r++) acc[db][r] *= alpha;
        m = mnew;

        bf16x8 pa0 = *(const bf16x8*)&P_lds[w][fr * 80 + fq * 8];
        bf16x8 pa1 = *(const bf16x8*)&P_lds[w][fr * 80 + 32 + fq * 8];
        __builtin_amdgcn_s_setprio(1);
        #pragma unroll
        for (int db = 0; db < 4; db++) {
            const int d = db * 16 + fr;
            bf16x8 vt0 = *(const bf16x8*)&Vt_lds[(d * 64 + fq * 8) ^ ((fr & 7) << 3)];
            bf16x8 vt1 = *(const bf16x8*)&Vt_lds[(d * 64 + 32 + fq * 8) ^ ((fr & 7) << 3)];
            acc[db] = __builtin_amdgcn_mfma_f32_16x16x32_bf16(vt0, pa0, acc[db], 0, 0, 0);
            acc[db] = __builtin_amdgcn_mfma_f32_16x16x32_bf16(vt1, pa1, acc[db], 0, 0, 0);
        }
        __builtin_amdgcn_s_setprio(0);
        __syncthreads();
    }

    const float inv_l = 1.f / l;
    bf16* orow = att + (size_t)(b * T_ + qrow) * D_ + h * 64;
    #pragma unroll
    for (int db = 0; db < 4; db++) {
        #pragma unroll
        for (int rp = 0; rp < 2; rp++) {
            unsigned u = pk_bf16(acc[db][rp * 2] * inv_l, acc[db][rp * 2 + 1] * inv_l);
            *(unsigned*)(orow + db * 16 + fq * 4 + rp * 2) = u;
        }
    }
}

// ---------------- host orchestration ----------------
extern "C" void kernel_launch(void* const* d_in, const int* in_sizes, int n_in,
                              void* d_out, int out_size, void* d_ws, size_t ws_size,
                              hipStream_t stream) {
    const int* idx      = (const int*)  d_in[0];
    const float* wte    = (const float*)d_in[1];
    const float* wpe    = (const float*)d_in[2];
    const float* ln1_g  = (const float*)d_in[3];
    const float* ln1_b  = (const float*)d_in[4];
    const float* attn_w = (const float*)d_in[5];
    const float* attn_b = (const float*)d_in[6];
    const float* aproj_w= (const float*)d_in[7];
    const float* aproj_b= (const float*)d_in[8];
    const float* ln2_g  = (const float*)d_in[9];
    const float* ln2_b  = (const float*)d_in[10];
    const float* fc_w   = (const float*)d_in[11];
    const float* fc_b   = (const float*)d_in[12];
    const float* mproj_w= (const float*)d_in[13];
    const float* mproj_b= (const float*)d_in[14];
    const float* lnf_g  = (const float*)d_in[15];
    const float* lnf_b  = (const float*)d_in[16];
    const float* lm_w   = (const float*)d_in[17];
    float* out = (float*)d_out;

    char* wsB = (char*)d_ws;
    float* x   = (float*)(wsB);                 // 6291456 B
    bf16*  big = (bf16*) (wsB + 6291456);       // 12582912 B
    bf16*  hbuf= (bf16*) (wsB + 18874368);      // 3145728 B
    bf16*  att = (bf16*) (wsB + 22020096);      // 3145728 B

    const size_t S_QKV = (size_t)2304 * 768, S_AP = (size_t)768 * 768;
    const size_t S_FC  = (size_t)3072 * 768, S_MP = (size_t)3072 * 768;
    const bool big_ws = ws_size >= 272302080ull;

    embed_kernel<<<BT_ / 4, 256, 0, stream>>>(idx, wte, wpe, x);

    if (big_ws) {
        bf16* w_qkv  = (bf16*)(wsB + 25165824);
        bf16* w_ap   = w_qkv + S_QKV * L_;
        bf16* w_fc   = w_ap  + S_AP  * L_;
        bf16* w_mp   = w_fc  + S_FC  * L_;
        bf16* lm_wt  = w_mp  + S_MP  * L_;      // [VPAD_,768]

        convT_kernel<<<dim3(72, 24, L_), 256, 0, stream>>>(attn_w, w_qkv, 768, 2304, 0, 2304, S_QKV, S_QKV);
        convT_kernel<<<dim3(24, 24, L_), 256, 0, stream>>>(aproj_w, w_ap, 768, 768, 0, 768, S_AP, S_AP);
        convT_kernel<<<dim3(96, 24, L_), 256, 0, stream>>>(fc_w, w_fc, 768, 3072, 0, 3072, S_FC, S_FC);
        convT_kernel<<<dim3(24, 96, L_), 256, 0, stream>>>(mproj_w, w_mp, 3072, 768, 0, 768, S_MP, S_MP);
        convT_kernel<<<dim3(VPAD_ / 32, 24, 1), 256, 0, stream>>>(lm_w, lm_wt, 768, V_, 0, V_, 0, 0);

        for (int l = 0; l < L_; l++) {
            lnorm_kernel<<<BT_ / 4, 256, 0, stream>>>(x, ln1_g + (size_t)l * D_, ln1_b + (size_t)l * D_, hbuf);
            gemm_qkv<<<16 * 36, 256, 0, stream>>>(
                hbuf, w_qkv + l * S_QKV, attn_b + (size_t)l * 3 * D_, nullptr, big, 768, 2304, 0, 2304, 16);
            fattn_kernel<<<dim3(16, 2 * H_), 256, 0, stream>>>(big, att);
            gemm_aproj<<<32 * 12, 256, 0, stream>>>(
                att, w_ap + l * S_AP, aproj_b + (size_t)l * D_, x, x, 768, 768, 0, 768, 32);
            lnorm_kernel<<<BT_ / 4, 256, 0, stream>>>(x, ln2_g + (size_t)l * D_, ln2_b + (size_t)l * D_, hbuf);
            gemm_fc<<<16 * 48, 256, 0, stream>>>(
                hbuf, w_fc + l * S_FC, fc_b + (size_t)l * 4 * D_, nullptr, big, 768, 3072, 0, 3072, 16);
            gemm_mproj<<<32 * 12, 256, 0, stream>>>(
                big, w_mp + l * S_MP, mproj_b + (size_t)l * D_, x, x, 3072, 768, 0, 768, 32);
        }

        lnorm_kernel<<<BT_ / 4, 256, 0, stream>>>(x, lnf_g, lnf_b, hbuf);
        gemm_lmhead<<<16 * (VPAD_ / 128), 512, 0, stream>>>(
            hbuf, lm_wt, nullptr, nullptr, out, 768, V_, 0, V_, 16);
    } else {
        // fallback: per-layer conversion into a 14.2 MB rotating buffer
        bf16* wbuf    = (bf16*)(wsB + 25165824);
        bf16* w_qkv   = wbuf;
        bf16* w_ap    = wbuf + S_QKV;
        bf16* w_fc    = w_ap + S_AP;
        bf16* w_mp    = w_fc + S_FC;

        for (int l = 0; l < L_; l++) {
            lnorm_kernel<<<BT_ / 4, 256, 0, stream>>>(x, ln1_g + (size_t)l * D_, ln1_b + (size_t)l * D_, hbuf);
            convT_kernel<<<dim3(72, 24, 1), 256, 0, stream>>>(
                attn_w + l * S_QKV, w_qkv, 768, 2304, 0, 2304, 0, 0);
            gemm_qkv<<<16 * 36, 256, 0, stream>>>(
                hbuf, w_qkv, attn_b + (size_t)l * 3 * D_, nullptr, big, 768, 2304, 0, 2304, 16);
            fattn_kernel<<<dim3(16, 2 * H_), 256, 0, stream>>>(big, att);
            convT_kernel<<<dim3(24, 24, 1), 256, 0, stream>>>(
                aproj_w + l * S_AP, w_ap, 768, 768, 0, 768, 0, 0);
            gemm_aproj<<<32 * 12, 256, 0, stream>>>(
                att, w_ap, aproj_b + (size_t)l * D_, x, x, 768, 768, 0, 768, 32);
            lnorm_kernel<<<BT_ / 4, 256, 0, stream>>>(x, ln2_g + (size_t)l * D_, ln2_b + (size_t)l * D_, hbuf);
            convT_kernel<<<dim3(96, 24, 1), 256, 0, stream>>>(
                fc_w + l * S_FC, w_fc, 768, 3072, 0, 3072, 0, 0);
            gemm_fc<<<16 * 48, 256, 0, stream>>>(
                hbuf, w_fc, fc_b + (size_t)l * 4 * D_, nullptr, big, 768, 3072, 0, 3072, 16);
            convT_kernel<<<dim3(24, 96, 1), 256, 0, stream>>>(
                mproj_w + l * S_MP, w_mp, 3072, 768, 0, 768, 0, 0);
            gemm_mproj<<<32 * 12, 256, 0, stream>>>(
                big, w_mp, mproj_b + (size_t)l * D_, x, x, 3072, 768, 0, 768, 32);
        }

        lnorm_kernel<<<BT_ / 4, 256, 0, stream>>>(x, lnf_g, lnf_b, hbuf);
        for (int c0 = 0; c0 < VPAD_; c0 += NCHUNK_) {
            int ncnt = (VPAD_ - c0 < NCHUNK_) ? (VPAD_ - c0) : NCHUNK_;
            convT_kernel<<<dim3(ncnt / 32, 24, 1), 256, 0, stream>>>(
                lm_w, wbuf, 768, V_, c0, V_, 0, 0);
            gemm_lmhead<<<16 * (ncnt / 128), 512, 0, stream>>>(
                hbuf, wbuf, nullptr, nullptr, out, 768, V_, c0, V_, 16);
        }
    }
}

// Round 19
// 1905.628 us; speedup vs baseline: 1.0092x; 1.0092x over previous
//
#include <hip/hip_runtime.h>
#include <hip/hip_bf16.h>
#include <math.h>

#define BT_   2048
#define D_    768
#define T_    1024
#define H_    12
#define HD_   64
#define L_    12
#define V_    50257
#define VPAD_ 50304    // 393*128
#define NCHUNK_ 7168   // 56*128

typedef __hip_bfloat16 bf16;
typedef short bf16x8 __attribute__((ext_vector_type(8)));  // 8 bf16 = 4 VGPRs
typedef short s16x4 __attribute__((ext_vector_type(4)));
typedef float f32x4 __attribute__((ext_vector_type(4)));

// ---------------- embedding: wave-per-row, float4 (G13) ----------------
__global__ __launch_bounds__(256) void embed_kernel(const int* __restrict__ idx,
                                                    const float* __restrict__ wte,
                                                    const float* __restrict__ wpe,
                                                    float* __restrict__ x) {
    const int bt   = blockIdx.x * 4 + (threadIdx.x >> 6);
    const int lane = threadIdx.x & 63;
    const int t    = bt & (T_ - 1);
    const int tok  = idx[bt];
    const float* wrow = wte + (size_t)tok * D_;
    const float* prow = wpe + (size_t)t * D_;
    float* xrow = x + (size_t)bt * D_;
    #pragma unroll
    for (int i = 0; i < 3; i++) {
        const int d0 = (i * 64 + lane) * 4;
        f32x4 a = *(const f32x4*)&wrow[d0];
        f32x4 p = *(const f32x4*)&prow[d0];
        #pragma unroll
        for (int e = 0; e < 4; e++) a[e] += p[e];
        *(f32x4*)&xrow[d0] = a;
    }
}

// ---------------- layernorm: wave-per-row, float4 loads, packed stores ----------------
__global__ __launch_bounds__(256) void lnorm_kernel(const float* __restrict__ in,
                                                    const float* __restrict__ g,
                                                    const float* __restrict__ b,
                                                    bf16* __restrict__ out) {
    const int row  = blockIdx.x * 4 + (threadIdx.x >> 6);
    const int lane = threadIdx.x & 63;
    const float* xr = in + (size_t)row * D_;
    f32x4 v[3];
    float s = 0.f, s2 = 0.f;
    #pragma unroll
    for (int i = 0; i < 3; i++) {
        v[i] = *(const f32x4*)&xr[(i * 64 + lane) * 4];
        #pragma unroll
        for (int e = 0; e < 4; e++) { s += v[i][e]; s2 += v[i][e] * v[i][e]; }
    }
    #pragma unroll
    for (int o = 32; o >= 1; o >>= 1) {
        s  += __shfl_xor(s,  o);
        s2 += __shfl_xor(s2, o);
    }
    const float mu   = s / D_;
    const float var  = s2 / D_ - mu * mu;
    const float rstd = rsqrtf(var + 1e-5f);
    bf16* orow = out + (size_t)row * D_;
    #pragma unroll
    for (int i = 0; i < 3; i++) {
        const int d0 = (i * 64 + lane) * 4;
        f32x4 gv = *(const f32x4*)&g[d0];
        f32x4 bv = *(const f32x4*)&b[d0];
        s16x4 u;
        #pragma unroll
        for (int e = 0; e < 4; e++) {
            bf16 h = __float2bfloat16((v[i][e] - mu) * rstd * gv[e] + bv[e]);
            u[e] = *(short*)&h;
        }
        *(s16x4*)&orow[d0] = u;
    }
}

// ---------------- transpose-convert: W fp32 [K,N] -> Wt bf16 [N,K]; z = layer ----------------
__global__ __launch_bounds__(256) void convT_kernel(const float* __restrict__ W,
                                                    bf16* __restrict__ Wt,
                                                    int K, int ldW, int n_src0, int Nreal,
                                                    size_t sW, size_t sT) {
    W  += (size_t)blockIdx.z * sW;
    Wt += (size_t)blockIdx.z * sT;
    __shared__ float t[32][33];
    int tx = threadIdx.x & 31, ty = threadIdx.x >> 5;  // ty 0..7
    int k0 = blockIdx.y * 32, n0 = blockIdx.x * 32;
    #pragma unroll
    for (int i = 0; i < 4; i++) {
        int k = k0 + ty + i * 8;
        int n = n_src0 + n0 + tx;
        t[ty + i * 8][tx] = (n < Nreal) ? W[(size_t)k * ldW + n] : 0.f;
    }
    __syncthreads();
    #pragma unroll
    for (int i = 0; i < 4; i++)
        Wt[(size_t)(n0 + ty + i * 8) * K + k0 + tx] = __float2bfloat16(t[tx][ty + i * 8]);
}

__device__ inline float gelu_f(float v) {
    const float c = 0.7978845608028654f;
    float u = c * (v + 0.044715f * v * v * v);
    return 0.5f * v * (1.f + tanhf(u));
}

__device__ inline void gload16(const void* g, void* l) {
    __builtin_amdgcn_global_load_lds((const __attribute__((address_space(1))) void*)g,
                                     (__attribute__((address_space(3))) void*)l, 16, 0, 0);
}

// ============ PIPE=3 BK=64 body — aproj/mproj (64x64; deep prefetch wins at K=3072) ====
template <int BM, int BN, int WM, int WN, int EPI, typename OT>
__device__ __attribute__((always_inline)) void gemm_body64(
        const bf16* __restrict__ A, const bf16* __restrict__ Bt,
        const float* __restrict__ bias, const float* res, OT* C,
        int K, int ldC, int n_off, int Ncap, int nx) {
    constexpr int NW = WM * WN;
    constexpr int MI = BM / WM / 16;
    constexpr int NJ = BN / WN / 16;
    constexpr int SA = (BM / 16) / NW;
    constexpr int SB = (BN / 16) / NW;
    constexpr int G  = 2 * (SA + SB);
    static_assert(SA >= 1 && SB >= 1, "stage mapping needs >=1 seg per wave");
    __shared__ __align__(16) short smem[3 * (BM + BN) * 64];
    short* Asm = smem;
    short* Bsm = smem + 3 * BM * 64;
    const int tid  = threadIdx.x;
    const int lane = tid & 63;
    const int wid  = tid >> 6;
    const int wm = wid / WN, wn = wid % WN;

    const int nwg = gridDim.x;
    const int bid = blockIdx.x;
    const int q8  = nwg >> 3, r8 = nwg & 7;
    const int xcd = bid & 7, off = bid >> 3;
    const int swz = (xcd < r8 ? xcd * (q8 + 1) : r8 * (q8 + 1) + (xcd - r8) * q8) + off;
    const int m0 = (swz % nx) * BM;
    const int n0 = (swz / nx) * BN;

    const int rS8 = lane >> 3;
    const int cS  = ((lane & 7) ^ rS8) * 8;
    const int fr = lane & 15;
    const int fq = lane >> 4;

    auto STAGE = [&](int buf, int k0) {
        #pragma unroll
        for (int s = 0; s < SA; s++) {
            const int seg = wid * SA + s;
            #pragma unroll
            for (int g = 0; g < 2; g++)
                gload16(A + (size_t)(m0 + seg * 16 + g * 8 + rS8) * K + k0 + cS,
                        &Asm[buf * BM * 64 + seg * 1024 + g * 512]);
        }
        #pragma unroll
        for (int s = 0; s < SB; s++) {
            const int seg = wid * SB + s;
            #pragma unroll
            for (int g = 0; g < 2; g++)
                gload16(Bt + (size_t)(n0 + seg * 16 + g * 8 + rS8) * K + k0 + cS,
                        &Bsm[buf * BN * 64 + seg * 1024 + g * 512]);
        }
    };

    f32x4 acc[MI][NJ] = {};

    auto COMPUTE = [&](int buf) {
        bf16x8 af[2][MI], bfr[2][NJ];
        #pragma unroll
        for (int kh = 0; kh < 2; kh++) {
            #pragma unroll
            for (int i = 0; i < MI; i++) {
                const int row = wm * (BM / WM) + i * 16 + fr;
                af[kh][i] = *(const bf16x8*)&Asm[buf * BM * 64 + row * 64 + (((kh * 4 + fq) ^ (fr & 7)) << 3)];
            }
            #pragma unroll
            for (int j = 0; j < NJ; j++) {
                const int row = wn * (BN / WN) + j * 16 + fr;
                bfr[kh][j] = *(const bf16x8*)&Bsm[buf * BN * 64 + row * 64 + (((kh * 4 + fq) ^ (fr & 7)) << 3)];
            }
        }
        __builtin_amdgcn_s_setprio(1);
        #pragma unroll
        for (int i = 0; i < MI; i++)
            #pragma unroll
            for (int j = 0; j < NJ; j++) {
                acc[i][j] = __builtin_amdgcn_mfma_f32_16x16x32_bf16(af[0][i], bfr[0][j], acc[i][j], 0, 0, 0);
                acc[i][j] = __builtin_amdgcn_mfma_f32_16x16x32_bf16(af[1][i], bfr[1][j], acc[i][j], 0, 0, 0);
            }
        __builtin_amdgcn_s_setprio(0);
    };

    const int nk = K / 64;
    STAGE(0, 0);
    STAGE(1, 64);
    int cur = 0;
    for (int ks = 0; ks < nk - 1; ks++) {
        asm volatile("s_waitcnt vmcnt(%0)" :: "n"(G) : "memory");
        __builtin_amdgcn_s_barrier();
        __builtin_amdgcn_sched_barrier(0);
        if (ks + 2 < nk) {
            int nxt = cur + 2; if (nxt >= 3) nxt -= 3;
            STAGE(nxt, (ks + 2) * 64);
        }
        COMPUTE(cur);
        cur = (cur + 1 == 3) ? 0 : cur + 1;
    }
    asm volatile("s_waitcnt vmcnt(0)" ::: "memory");
    __builtin_amdgcn_s_barrier();
    __builtin_amdgcn_sched_barrier(0);
    COMPUTE(cur);

    #pragma unroll
    for (int j = 0; j < NJ; j++) {
        const int col = n_off + n0 + wn * (BN / WN) + j * 16 + fr;
        if (col >= Ncap) continue;
        const float bb = (EPI == 3) ? 0.f : bias[col];
        #pragma unroll
        for (int i = 0; i < MI; i++) {
            #pragma unroll
            for (int r = 0; r < 4; r++) {
                const int row = m0 + wm * (BM / WM) + i * 16 + fq * 4 + r;
                float v = acc[i][j][r] + bb;
                if (EPI == 1) v += res[(size_t)row * ldC + col];
                if (EPI == 2) v = gelu_f(v);
                if constexpr (sizeof(OT) == 2)
                    C[(size_t)row * ldC + col] = __float2bfloat16(v);
                else
                    C[(size_t)row * ldC + col] = v;
            }
        }
    }
}

// ============ PIPE=2 BK=64 body — qkv/fc (128x64: LDS 49KB -> 3 blk/CU) ============
template <int BM, int BN, int WM, int WN, int EPI, typename OT>
__device__ __attribute__((always_inline)) void gemm_body64_p2(
        const bf16* __restrict__ A, const bf16* __restrict__ Bt,
        const float* __restrict__ bias, const float* res, OT* C,
        int K, int ldC, int n_off, int Ncap, int nx) {
    constexpr int NW = WM * WN;
    constexpr int MI = BM / WM / 16;
    constexpr int NJ = BN / WN / 16;
    constexpr int SA = (BM / 16) / NW;
    constexpr int SB = (BN / 16) / NW;
    constexpr int G  = 2 * (SA + SB);
    static_assert(SA >= 1 && SB >= 1, "stage mapping needs >=1 seg per wave");
    __shared__ __align__(16) short smem[2 * (BM + BN) * 64];
    short* Asm = smem;
    short* Bsm = smem + 2 * BM * 64;
    const int tid  = threadIdx.x;
    const int lane = tid & 63;
    const int wid  = tid >> 6;
    const int wm = wid / WN, wn = wid % WN;

    const int nwg = gridDim.x;
    const int bid = blockIdx.x;
    const int q8  = nwg >> 3, r8 = nwg & 7;
    const int xcd = bid & 7, off = bid >> 3;
    const int swz = (xcd < r8 ? xcd * (q8 + 1) : r8 * (q8 + 1) + (xcd - r8) * q8) + off;
    const int m0 = (swz % nx) * BM;
    const int n0 = (swz / nx) * BN;

    const int rS8 = lane >> 3;
    const int cS  = ((lane & 7) ^ rS8) * 8;
    const int fr = lane & 15;
    const int fq = lane >> 4;

    auto STAGE = [&](int buf, int k0) {
        #pragma unroll
        for (int s = 0; s < SA; s++) {
            const int seg = wid * SA + s;
            #pragma unroll
            for (int g = 0; g < 2; g++)
                gload16(A + (size_t)(m0 + seg * 16 + g * 8 + rS8) * K + k0 + cS,
                        &Asm[buf * BM * 64 + seg * 1024 + g * 512]);
        }
        #pragma unroll
        for (int s = 0; s < SB; s++) {
            const int seg = wid * SB + s;
            #pragma unroll
            for (int g = 0; g < 2; g++)
                gload16(Bt + (size_t)(n0 + seg * 16 + g * 8 + rS8) * K + k0 + cS,
                        &Bsm[buf * BN * 64 + seg * 1024 + g * 512]);
        }
    };

    f32x4 acc[MI][NJ] = {};

    auto COMPUTE = [&](int buf) {
        bf16x8 af[2][MI], bfr[2][NJ];
        #pragma unroll
        for (int kh = 0; kh < 2; kh++) {
            #pragma unroll
            for (int i = 0; i < MI; i++) {
                const int row = wm * (BM / WM) + i * 16 + fr;
                af[kh][i] = *(const bf16x8*)&Asm[buf * BM * 64 + row * 64 + (((kh * 4 + fq) ^ (fr & 7)) << 3)];
            }
            #pragma unroll
            for (int j = 0; j < NJ; j++) {
                const int row = wn * (BN / WN) + j * 16 + fr;
                bfr[kh][j] = *(const bf16x8*)&Bsm[buf * BN * 64 + row * 64 + (((kh * 4 + fq) ^ (fr & 7)) << 3)];
            }
        }
        __builtin_amdgcn_s_setprio(1);
        #pragma unroll
        for (int i = 0; i < MI; i++)
            #pragma unroll
            for (int j = 0; j < NJ; j++) {
                acc[i][j] = __builtin_amdgcn_mfma_f32_16x16x32_bf16(af[0][i], bfr[0][j], acc[i][j], 0, 0, 0);
                acc[i][j] = __builtin_amdgcn_mfma_f32_16x16x32_bf16(af[1][i], bfr[1][j], acc[i][j], 0, 0, 0);
            }
        __builtin_amdgcn_s_setprio(0);
    };

    const int nk = K / 64;
    STAGE(0, 0);
    STAGE(1, 64);
    int cur = 0;
    for (int ks = 0; ks < nk - 1; ks++) {
        asm volatile("s_waitcnt vmcnt(%0)" :: "n"(G) : "memory");   // stage ks landed
        __builtin_amdgcn_s_barrier();
        __builtin_amdgcn_sched_barrier(0);
        COMPUTE(cur);
        __builtin_amdgcn_sched_barrier(0);
        __builtin_amdgcn_s_barrier();           // all waves done reading buf[cur]
        __builtin_amdgcn_sched_barrier(0);
        if (ks + 2 < nk) STAGE(cur, (ks + 2) * 64);
        cur ^= 1;
    }
    asm volatile("s_waitcnt vmcnt(0)" ::: "memory");
    __builtin_amdgcn_s_barrier();
    __builtin_amdgcn_sched_barrier(0);
    COMPUTE(cur);

    #pragma unroll
    for (int j = 0; j < NJ; j++) {
        const int col = n_off + n0 + wn * (BN / WN) + j * 16 + fr;
        if (col >= Ncap) continue;
        const float bb = (EPI == 3) ? 0.f : bias[col];
        #pragma unroll
        for (int i = 0; i < MI; i++) {
            #pragma unroll
            for (int r = 0; r < 4; r++) {
                const int row = m0 + wm * (BM / WM) + i * 16 + fq * 4 + r;
                float v = acc[i][j][r] + bb;
                if (EPI == 1) v += res[(size_t)row * ldC + col];
                if (EPI == 2) v = gelu_f(v);
                if constexpr (sizeof(OT) == 2)
                    C[(size_t)row * ldC + col] = __float2bfloat16(v);
                else
                    C[(size_t)row * ldC + col] = v;
            }
        }
    }
}

// ============ BK=32 body — LM head only (pinned ~300us memory floor) ============
template <int BM, int BN, int WM, int WN, int EPI, int NGRP, typename OT>
__device__ __attribute__((always_inline)) void gemm_body(
        const bf16* __restrict__ A, const bf16* __restrict__ Bt,
        const float* __restrict__ bias, const float* res, OT* C,
        int K, int ldC, int n_off, int Ncap, int nx) {
    constexpr int NW = WM * WN;
    constexpr int MI = BM / WM / 16;
    constexpr int NJ = BN / WN / 16;
    constexpr int GA = (BM / 16) / NW;
    constexpr int GB = (BN / 16) / NW;
    constexpr int G  = GA + GB;
    static_assert(GA >= 1 && GB >= 1, "stage mapping needs >=1 seg per wave");
    __shared__ __align__(16) short smem[3 * (BM + BN) * 32];
    short* Asm = smem;
    short* Bsm = smem + 3 * BM * 32;
    const int tid  = threadIdx.x;
    const int lane = tid & 63;
    const int wid  = tid >> 6;
    const int wm = wid / WN, wn = wid % WN;

    const int nwg = gridDim.x;
    const int bid = blockIdx.x;
    const int q8  = nwg >> 3, r8 = nwg & 7;
    const int xcd = bid & 7, off = bid >> 3;
    const int swz = (xcd < r8 ? xcd * (q8 + 1) : r8 * (q8 + 1) + (xcd - r8) * q8) + off;
    int m0, n0;
    if constexpr (NGRP > 0) {
        const int Gsz = nx * NGRP;
        const int g = swz / Gsz, r = swz % Gsz;
        m0 = (r % nx) * BM;
        n0 = (g * NGRP + r / nx) * BN;
    } else {
        m0 = (swz % nx) * BM;
        n0 = (swz / nx) * BN;
    }

    const int rS = lane >> 2;
    const int cS = ((lane & 3) ^ ((lane >> 3) & 3)) * 8;
    const int fr = lane & 15;
    const int fq = lane >> 4;
    const int rc = (fq ^ ((fr >> 1) & 3)) * 8;

    auto STAGE = [&](int buf, int k0) {
        #pragma unroll
        for (int s = 0; s < GA; s++) {
            const int seg = wid * GA + s;
            gload16(A + (size_t)(m0 + seg * 16 + rS) * K + k0 + cS, &Asm[buf * BM * 32 + seg * 512]);
        }
        #pragma unroll
        for (int s = 0; s < GB; s++) {
            const int seg = wid * GB + s;
            gload16(Bt + (size_t)(n0 + seg * 16 + rS) * K + k0 + cS, &Bsm[buf * BN * 32 + seg * 512]);
        }
    };

    f32x4 acc[MI][NJ] = {};

    auto COMPUTE = [&](int buf) {
        bf16x8 af[MI], bfr[NJ];
        #pragma unroll
        for (int i = 0; i < MI; i++)
            af[i] = *(const bf16x8*)&Asm[buf * BM * 32 + (wm * (BM / WM) + i * 16 + fr) * 32 + rc];
        #pragma unroll
        for (int j = 0; j < NJ; j++)
            bfr[j] = *(const bf16x8*)&Bsm[buf * BN * 32 + (wn * (BN / WN) + j * 16 + fr) * 32 + rc];
        __builtin_amdgcn_s_setprio(1);
        #pragma unroll
        for (int i = 0; i < MI; i++)
            #pragma unroll
            for (int j = 0; j < NJ; j++)
                acc[i][j] = __builtin_amdgcn_mfma_f32_16x16x32_bf16(af[i], bfr[j], acc[i][j], 0, 0, 0);
        __builtin_amdgcn_s_setprio(0);
    };

    const int nk = K / 32;
    STAGE(0, 0);
    STAGE(1, 32);
    int cur = 0;
    for (int ks = 0; ks < nk - 1; ks++) {
        asm volatile("s_waitcnt vmcnt(%0)" :: "n"(G) : "memory");
        __builtin_amdgcn_s_barrier();
        __builtin_amdgcn_sched_barrier(0);
        if (ks + 2 < nk) {
            int nxt = cur + 2; if (nxt >= 3) nxt -= 3;
            STAGE(nxt, (ks + 2) * 32);
        }
        COMPUTE(cur);
        cur = (cur + 1 == 3) ? 0 : cur + 1;
    }
    asm volatile("s_waitcnt vmcnt(0)" ::: "memory");
    __builtin_amdgcn_s_barrier();
    __builtin_amdgcn_sched_barrier(0);
    COMPUTE(cur);

    #pragma unroll
    for (int j = 0; j < NJ; j++) {
        const int col = n_off + n0 + wn * (BN / WN) + j * 16 + fr;
        if (col >= Ncap) continue;
        const float bb = (EPI == 3) ? 0.f : bias[col];
        #pragma unroll
        for (int i = 0; i < MI; i++) {
            #pragma unroll
            for (int r = 0; r < 4; r++) {
                const int row = m0 + wm * (BM / WM) + i * 16 + fq * 4 + r;
                float v = acc[i][j][r] + bb;
                if (EPI == 1) v += res[(size_t)row * ldC + col];
                if (EPI == 2) v = gelu_f(v);
                if constexpr (sizeof(OT) == 2)
                    C[(size_t)row * ldC + col] = __float2bfloat16(v);
                else
                    C[(size_t)row * ldC + col] = v;
            }
        }
    }
}

// Named instantiations — r17 best configuration.
__global__ __launch_bounds__(256) void gemm_qkv(const bf16* A, const bf16* Bt, const float* bias,
                                                const float* res, bf16* C, int K, int ldC,
                                                int n_off, int Ncap, int nx) {
    gemm_body64_p2<128, 64, 2, 2, 0, bf16>(A, Bt, bias, res, C, K, ldC, n_off, Ncap, nx);
}
__global__ __launch_bounds__(256) void gemm_aproj(const bf16* A, const bf16* Bt, const float* bias,
                                                  const float* res, float* C, int K, int ldC,
                                                  int n_off, int Ncap, int nx) {
    gemm_body64<64, 64, 2, 2, 1, float>(A, Bt, bias, res, C, K, ldC, n_off, Ncap, nx);
}
__global__ __launch_bounds__(256) void gemm_fc(const bf16* A, const bf16* Bt, const float* bias,
                                               const float* res, bf16* C, int K, int ldC,
                                               int n_off, int Ncap, int nx) {
    gemm_body64_p2<128, 64, 2, 2, 2, bf16>(A, Bt, bias, res, C, K, ldC, n_off, Ncap, nx);
}
__global__ __launch_bounds__(256) void gemm_mproj(const bf16* A, const bf16* Bt, const float* bias,
                                                  const float* res, float* C, int K, int ldC,
                                                  int n_off, int Ncap, int nx) {
    gemm_body64<64, 64, 2, 2, 1, float>(A, Bt, bias, res, C, K, ldC, n_off, Ncap, nx);
}
__global__ __launch_bounds__(512) void gemm_lmhead(const bf16* A, const bf16* Bt, const float* bias,
                                                   const float* res, float* C, int K, int ldC,
                                                   int n_off, int Ncap, int nx) {
    gemm_body<128, 128, 4, 2, 3, 4, float>(A, Bt, bias, res, C, K, ldC, n_off, Ncap, nx);
}

// ---------------- MFMA flash attention (+ T5 setprio, r15-proven) ----------
__device__ inline unsigned pk_bf16(float a, float b) {
    __hip_bfloat16 ha = __float2bfloat16(a), hb = __float2bfloat16(b);
    unsigned short ua = *(unsigned short*)&ha, ub = *(unsigned short*)&hb;
    return (unsigned)ua | ((unsigned)ub << 16);
}

__global__ __launch_bounds__(256) void fattn_kernel(const bf16* __restrict__ qkv,
                                                    bf16* __restrict__ att) {
    const int qi  = 15 - blockIdx.x;
    const int bh  = blockIdx.y;
    const int h   = bh % H_;
    const int b   = bh / H_;
    const int q0  = qi * 64;
    const int tid = threadIdx.x;
    const int lane = tid & 63;
    const int w   = tid >> 6;
    const int fr  = lane & 15;
    const int fq  = lane >> 4;

    __shared__ __align__(16) short K_lds[64 * 64];
    __shared__ __align__(16) short Vt_lds[64 * 64];
    __shared__ __align__(16) short P_lds[4][16 * 80];

    const size_t base = (size_t)b * T_ * 2304;
    const int qrow = q0 + w * 16 + fr;

    bf16x8 qf[2];
    qf[0] = *(const bf16x8*)(qkv + base + (size_t)qrow * 2304 + h * 64 + fq * 8);
    qf[1] = *(const bf16x8*)(qkv + base + (size_t)qrow * 2304 + h * 64 + 32 + fq * 8);

    const int vj  = tid >> 2;
    const int vd0 = (tid & 3) * 16;

    f32x4 acc[4] = {};
    float m = -1e30f, l = 0.f;

    const int nt = qi + 1;
    for (int kt = 0; kt < nt; kt++) {
        const int j0 = kt * 64;

        #pragma unroll
        for (int p = 0; p < 2; p++) {
            const int jl  = p * 32 + w * 8 + (lane >> 3);
            const int chg = (lane & 7) ^ (jl & 7);
            gload16(qkv + base + (size_t)(j0 + jl) * 2304 + D_ + h * 64 + chg * 8,
                    &K_lds[(p * 32 + w * 8) * 64]);
        }
        {
            const bf16* vsrc = qkv + base + (size_t)(j0 + vj) * 2304 + 2 * D_ + h * 64 + vd0;
            bf16x8 v0 = *(const bf16x8*)vsrc;
            bf16x8 v1 = *(const bf16x8*)(vsrc + 8);
            #pragma unroll
            for (int e = 0; e < 8; e++) {
                Vt_lds[((vd0 + e) * 64 + vj) ^ (e << 3)]     = v0[e];
                Vt_lds[((vd0 + 8 + e) * 64 + vj) ^ (e << 3)] = v1[e];
            }
        }
        __syncthreads();

        f32x4 s[4];
        __builtin_amdgcn_s_setprio(1);
        #pragma unroll
        for (int jb = 0; jb < 4; jb++) {
            const int j = jb * 16 + fr;
            bf16x8 k0 = *(const bf16x8*)&K_lds[j * 64 + (((0 + fq) ^ (fr & 7)) << 3)];
            bf16x8 k1 = *(const bf16x8*)&K_lds[j * 64 + (((4 + fq) ^ (fr & 7)) << 3)];
            f32x4 z = {};
            z = __builtin_amdgcn_mfma_f32_16x16x32_bf16(k0, qf[0], z, 0, 0, 0);
            s[jb] = __builtin_amdgcn_mfma_f32_16x16x32_bf16(k1, qf[1], z, 0, 0, 0);
        }
        __builtin_amdgcn_s_setprio(0);

        const bool need_mask = (j0 + 63 > q0 + w * 16);
        float mx = -1e30f;
        #pragma unroll
        for (int jb = 0; jb < 4; jb++) {
            #pragma unroll
            for (int r = 0; r < 4; r++) {
                float v = s[jb][r] * 0.125f;
                if (need_mask && (j0 + jb * 16 + fq * 4 + r > qrow)) v = -1e30f;
                s[jb][r] = v;
                mx = fmaxf(mx, v);
            }
        }
        mx = fmaxf(mx, __shfl_xor(mx, 16));
        mx = fmaxf(mx, __shfl_xor(mx, 32));

        const float mnew  = fmaxf(m, mx);
        const float alpha = __expf(m - mnew);

        float ts = 0.f;
        #pragma unroll
        for (int jb = 0; jb < 4; jb++) {
            #pragma unroll
            for (int r = 0; r < 4; r++) {
                s[jb][r] = __expf(s[jb][r] - mnew);
                ts += s[jb][r];
            }
            *(unsigned*)&P_lds[w][fr * 80 + jb * 16 + fq * 4]     = pk_bf16(s[jb][0], s[jb][1]);
            *(unsigned*)&P_lds[w][fr * 80 + jb * 16 + fq * 4 + 2] = pk_bf16(s[jb][2], s[jb][3]);
        }
        ts += __shfl_xor(ts, 16);
        ts += __shfl_xor(ts, 32);
        l = l * alpha + ts;
        #pragma unroll
        for (int db = 0; db < 4; db++)
            #pragma unroll
            for (int r = 0; r < 4; r++) acc[db][r] *= alpha;
        m = mnew;

        bf16x8 pa0 = *(const bf16x8*)&P_lds[w][fr * 80 + fq * 8];
        bf16x8 pa1 = *(const bf16x8*)&P_lds[w][fr * 80 + 32 + fq * 8];
        __builtin_amdgcn_s_setprio(1);
        #pragma unroll
        for (int db = 0; db < 4; db++) {
            const int d = db * 16 + fr;
            bf16x8 vt0 = *(const bf16x8*)&Vt_lds[(d * 64 + fq * 8) ^ ((fr & 7) << 3)];
            bf16x8 vt1 = *(const bf16x8*)&Vt_lds[(d * 64 + 32 + fq * 8) ^ ((fr & 7) << 3)];
            acc[db] = __builtin_amdgcn_mfma_f32_16x16x32_bf16(vt0, pa0, acc[db], 0, 0, 0);
            acc[db] = __builtin_amdgcn_mfma_f32_16x16x32_bf16(vt1, pa1, acc[db], 0, 0, 0);
        }
        __builtin_amdgcn_s_setprio(0);
        __syncthreads();
    }

    const float inv_l = 1.f / l;
    bf16* orow = att + (size_t)(b * T_ + qrow) * D_ + h * 64;
    #pragma unroll
    for (int db = 0; db < 4; db++) {
        #pragma unroll
        for (int rp = 0; rp < 2; rp++) {
            unsigned u = pk_bf16(acc[db][rp * 2] * inv_l, acc[db][rp * 2 + 1] * inv_l);
            *(unsigned*)(orow + db * 16 + fq * 4 + rp * 2) = u;
        }
    }
}

// ---------------- host orchestration ----------------
extern "C" void kernel_launch(void* const* d_in, const int* in_sizes, int n_in,
                              void* d_out, int out_size, void* d_ws, size_t ws_size,
                              hipStream_t stream) {
    const int* idx      = (const int*)  d_in[0];
    const float* wte    = (const float*)d_in[1];
    const float* wpe    = (const float*)d_in[2];
    const float* ln1_g  = (const float*)d_in[3];
    const float* ln1_b  = (const float*)d_in[4];
    const float* attn_w = (const float*)d_in[5];
    const float* attn_b = (const float*)d_in[6];
    const float* aproj_w= (const float*)d_in[7];
    const float* aproj_b= (const float*)d_in[8];
    const float* ln2_g  = (const float*)d_in[9];
    const float* ln2_b  = (const float*)d_in[10];
    const float* fc_w   = (const float*)d_in[11];
    const float* fc_b   = (const float*)d_in[12];
    const float* mproj_w= (const float*)d_in[13];
    const float* mproj_b= (const float*)d_in[14];
    const float* lnf_g  = (const float*)d_in[15];
    const float* lnf_b  = (const float*)d_in[16];
    const float* lm_w   = (const float*)d_in[17];
    float* out = (float*)d_out;

    char* wsB = (char*)d_ws;
    float* x   = (float*)(wsB);                 // 6291456 B
    bf16*  big = (bf16*) (wsB + 6291456);       // 12582912 B
    bf16*  hbuf= (bf16*) (wsB + 18874368);      // 3145728 B
    bf16*  att = (bf16*) (wsB + 22020096);      // 3145728 B

    const size_t S_QKV = (size_t)2304 * 768, S_AP = (size_t)768 * 768;
    const size_t S_FC  = (size_t)3072 * 768, S_MP = (size_t)3072 * 768;
    const bool big_ws = ws_size >= 272302080ull;

    embed_kernel<<<BT_ / 4, 256, 0, stream>>>(idx, wte, wpe, x);

    if (big_ws) {
        bf16* w_qkv  = (bf16*)(wsB + 25165824);
        bf16* w_ap   = w_qkv + S_QKV * L_;
        bf16* w_fc   = w_ap  + S_AP  * L_;
        bf16* w_mp   = w_fc  + S_FC  * L_;
        bf16* lm_wt  = w_mp  + S_MP  * L_;      // [VPAD_,768]

        convT_kernel<<<dim3(72, 24, L_), 256, 0, stream>>>(attn_w, w_qkv, 768, 2304, 0, 2304, S_QKV, S_QKV);
        convT_kernel<<<dim3(24, 24, L_), 256, 0, stream>>>(aproj_w, w_ap, 768, 768, 0, 768, S_AP, S_AP);
        convT_kernel<<<dim3(96, 24, L_), 256, 0, stream>>>(fc_w, w_fc, 768, 3072, 0, 3072, S_FC, S_FC);
        convT_kernel<<<dim3(24, 96, L_), 256, 0, stream>>>(mproj_w, w_mp, 3072, 768, 0, 768, S_MP, S_MP);
        convT_kernel<<<dim3(VPAD_ / 32, 24, 1), 256, 0, stream>>>(lm_w, lm_wt, 768, V_, 0, V_, 0, 0);

        for (int l = 0; l < L_; l++) {
            lnorm_kernel<<<BT_ / 4, 256, 0, stream>>>(x, ln1_g + (size_t)l * D_, ln1_b + (size_t)l * D_, hbuf);
            gemm_qkv<<<16 * 36, 256, 0, stream>>>(
                hbuf, w_qkv + l * S_QKV, attn_b + (size_t)l * 3 * D_, nullptr, big, 768, 2304, 0, 2304, 16);
            fattn_kernel<<<dim3(16, 2 * H_), 256, 0, stream>>>(big, att);
            gemm_aproj<<<32 * 12, 256, 0, stream>>>(
                att, w_ap + l * S_AP, aproj_b + (size_t)l * D_, x, x, 768, 768, 0, 768, 32);
            lnorm_kernel<<<BT_ / 4, 256, 0, stream>>>(x, ln2_g + (size_t)l * D_, ln2_b + (size_t)l * D_, hbuf);
            gemm_fc<<<16 * 48, 256, 0, stream>>>(
                hbuf, w_fc + l * S_FC, fc_b + (size_t)l * 4 * D_, nullptr, big, 768, 3072, 0, 3072, 16);
            gemm_mproj<<<32 * 12, 256, 0, stream>>>(
                big, w_mp + l * S_MP, mproj_b + (size_t)l * D_, x, x, 3072, 768, 0, 768, 32);
        }

        lnorm_kernel<<<BT_ / 4, 256, 0, stream>>>(x, lnf_g, lnf_b, hbuf);
        gemm_lmhead<<<16 * (VPAD_ / 128), 512, 0, stream>>>(
            hbuf, lm_wt, nullptr, nullptr, out, 768, V_, 0, V_, 16);
    } else {
        // fallback: per-layer conversion into a 14.2 MB rotating buffer
        bf16* wbuf    = (bf16*)(wsB + 25165824);
        bf16* w_qkv   = wbuf;
        bf16* w_ap    = wbuf + S_QKV;
        bf16* w_fc    = w_ap + S_AP;
        bf16* w_mp    = w_fc + S_FC;

        for (int l = 0; l < L_; l++) {
            lnorm_kernel<<<BT_ / 4, 256, 0, stream>>>(x, ln1_g + (size_t)l * D_, ln1_b + (size_t)l * D_, hbuf);
            convT_kernel<<<dim3(72, 24, 1), 256, 0, stream>>>(
                attn_w + l * S_QKV, w_qkv, 768, 2304, 0, 2304, 0, 0);
            gemm_qkv<<<16 * 36, 256, 0, stream>>>(
                hbuf, w_qkv, attn_b + (size_t)l * 3 * D_, nullptr, big, 768, 2304, 0, 2304, 16);
            fattn_kernel<<<dim3(16, 2 * H_), 256, 0, stream>>>(big, att);
            convT_kernel<<<dim3(24, 24, 1), 256, 0, stream>>>(
                aproj_w + l * S_AP, w_ap, 768, 768, 0, 768, 0, 0);
            gemm_aproj<<<32 * 12, 256, 0, stream>>>(
                att, w_ap, aproj_b + (size_t)l * D_, x, x, 768, 768, 0, 768, 32);
            lnorm_kernel<<<BT_ / 4, 256, 0, stream>>>(x, ln2_g + (size_t)l * D_, ln2_b + (size_t)l * D_, hbuf);
            convT_kernel<<<dim3(96, 24, 1), 256, 0, stream>>>(
                fc_w + l * S_FC, w_fc, 768, 3072, 0, 3072, 0, 0);
            gemm_fc<<<16 * 48, 256, 0, stream>>>(
                hbuf, w_fc, fc_b + (size_t)l * 4 * D_, nullptr, big, 768, 3072, 0, 3072, 16);
            convT_kernel<<<dim3(24, 96, 1), 256, 0, stream>>>(
                mproj_w + l * S_MP, w_mp, 3072, 768, 0, 768, 0, 0);
            gemm_mproj<<<32 * 12, 256, 0, stream>>>(
                big, w_mp, mproj_b + (size_t)l * D_, x, x, 3072, 768, 0, 768, 32);
        }

        lnorm_kernel<<<BT_ / 4, 256, 0, stream>>>(x, lnf_g, lnf_b, hbuf);
        for (int c0 = 0; c0 < VPAD_; c0 += NCHUNK_) {
            int ncnt = (VPAD_ - c0 < NCHUNK_) ? (VPAD_ - c0) : NCHUNK_;
            convT_kernel<<<dim3(ncnt / 32, 24, 1), 256, 0, stream>>>(
                lm_w, wbuf, 768, V_, c0, V_, 0, 0);
            gemm_lmhead<<<16 * (ncnt / 128), 512, 0, stream>>>(
                hbuf, wbuf, nullptr, nullptr, out, 768, V_, c0, V_, 16);
        }
    }
}